// Round 3
// baseline (5934.640 us; speedup 1.0000x reference)
//
#include <hip/hip_runtime.h>
#include <stdint.h>

typedef __attribute__((ext_vector_type(8))) short short8;
typedef __attribute__((ext_vector_type(4))) float f32x4;
typedef __attribute__((ext_vector_type(4))) unsigned short u16x4;

// Problem constants: T=512, B=64, D=768, H=768, 4H=3072

// ws layout (bytes, all 256-aligned)
#define OFF_XBF   0UL
#define SZ_XBF    (512UL*64*768*2)
#define OFF_WXB   (OFF_XBF + SZ_XBF)
#define SZ_WB     (3072UL*768*2)
#define OFF_WHB   (OFF_WXB + SZ_WB)
#define OFF_BALL  (OFF_WHB + SZ_WB)
#define SZ_BALL   (3072UL*4)
#define OFF_XG    (OFF_BALL + SZ_BALL)
#define SZ_XG     (512UL*3072*64*2)
#define OFF_HBUF  (OFF_XG + SZ_XG)
#define SZ_HBUF   (2UL*64*768*2)
#define OFF_CST   (OFF_HBUF + SZ_HBUF)
#define SZ_CST    (64UL*768*4)

__device__ __forceinline__ float bf2f(unsigned short u){
  union{unsigned int i; float f;} v; v.i = ((unsigned int)u)<<16; return v.f;
}
__device__ __forceinline__ unsigned short f2bf(float f){
  union{float f; unsigned int i;} v; v.f = f;
  unsigned int x = v.i;
  return (unsigned short)((x + 0x7fffu + ((x>>16)&1u)) >> 16);
}
__device__ __forceinline__ float sigm(float x){ return 1.0f/(1.0f + __expf(-x)); }
// overflow-safe tanh: large |x| -> exp -> inf -> r=1, copysign fixes sign
__device__ __forceinline__ float tanh_s(float x){
  float e = __expf(2.0f*fabsf(x));
  float r = 1.0f - 2.0f/(e+1.0f);
  return copysignf(r, x);
}
__device__ __forceinline__ f32x4 mfma16(short8 a, short8 b, f32x4 c){
  return __builtin_amdgcn_mfma_f32_16x16x32_bf16(a, b, c, 0, 0, 0);
}

// ---- converters ----
__global__ void k_conv_x(const float* __restrict__ x, unsigned short* __restrict__ xb, int n4){
  int i = blockIdx.x*blockDim.x + threadIdx.x;
  if (i >= n4) return;
  float4 v = ((const float4*)x)[i];
  u16x4 o = { f2bf(v.x), f2bf(v.y), f2bf(v.z), f2bf(v.w) };
  *(u16x4*)(xb + (size_t)i*4) = o;
}

__global__ void k_conv_w(const float* __restrict__ Wf, const float* __restrict__ Wi,
                         const float* __restrict__ Wg, const float* __restrict__ Wo,
                         unsigned short* __restrict__ Wxb, unsigned short* __restrict__ Whb){
  int i = blockIdx.x*blockDim.x + threadIdx.x;
  if (i >= 3072*192) return;
  int gj = i / 192; int kc = (i % 192)*4;
  int g = gj / 768, j = gj % 768;
  const float* W = (g==0)?Wf:(g==1)?Wi:(g==2)?Wg:Wo;
  float4 vx = *(const float4*)(W + (size_t)j*1536 + kc);
  float4 vh = *(const float4*)(W + (size_t)j*1536 + 768 + kc);
  u16x4 ox = {f2bf(vx.x),f2bf(vx.y),f2bf(vx.z),f2bf(vx.w)};
  u16x4 oh = {f2bf(vh.x),f2bf(vh.y),f2bf(vh.z),f2bf(vh.w)};
  *(u16x4*)(Wxb + (size_t)gj*768 + kc) = ox;
  *(u16x4*)(Whb + (size_t)gj*768 + kc) = oh;
}

__global__ void k_conv_b(const float* __restrict__ b0, const float* __restrict__ b1,
                         const float* __restrict__ b2, const float* __restrict__ b3,
                         float* __restrict__ ball){
  int i = blockIdx.x*blockDim.x + threadIdx.x;
  if (i >= 3072) return;
  int g = i/768, j = i%768;
  const float* b = (g==0)?b0:(g==1)?b1:(g==2)?b2:b3;
  ball[i] = b[j];
}

// ---- phase 1: Xg[t][gj][b] = (x @ Wx^T), bf16, no bias ----
__global__ __launch_bounds__(256) void k_gemm_x(const unsigned short* __restrict__ xb,
        const unsigned short* __restrict__ Wxb, unsigned short* __restrict__ Xg){
  __shared__ __align__(16) short Ald[128*32];
  __shared__ __align__(16) short Bld[128*32];
  int blk = blockIdx.x;
  int bm = blk / 24, bn = blk % 24;     // consecutive blocks share A-panel (L2)
  size_t Mbase = (size_t)bm*128; int Nbase = bn*128;
  int tid = threadIdx.x; int w = tid>>6, l = tid&63;
  int wm = w&1, wn = w>>1, lr = l&15, lg = l>>4;
  f32x4 acc[4][4];
  #pragma unroll
  for (int a=0;a<4;++a)
    #pragma unroll
    for(int b2=0;b2<4;++b2) acc[a][b2] = (f32x4){0.f,0.f,0.f,0.f};
  int c0i = tid, c1i = tid+256;
  int r0 = c0i>>2, o0 = (c0i&3)*8;
  int r1 = c1i>>2, o1 = (c1i&3)*8;
  for (int kt=0; kt<24; ++kt) {
    int k0 = kt*32;
    short8 a0 = *(const short8*)(xb + (Mbase + r0)*768 + k0 + o0);
    short8 a1 = *(const short8*)(xb + (Mbase + r1)*768 + k0 + o1);
    short8 b0 = *(const short8*)(Wxb + (size_t)(Nbase + r0)*768 + k0 + o0);
    short8 b1 = *(const short8*)(Wxb + (size_t)(Nbase + r1)*768 + k0 + o1);
    __syncthreads();
    *(short8*)(Ald + r0*32 + o0) = a0;
    *(short8*)(Ald + r1*32 + o1) = a1;
    *(short8*)(Bld + r0*32 + o0) = b0;
    *(short8*)(Bld + r1*32 + o1) = b1;
    __syncthreads();
    short8 af[4], bfr[4];
    #pragma unroll
    for (int mi=0;mi<4;++mi) af[mi] = *(const short8*)(Ald + (wm*64+mi*16+lr)*32 + lg*8);
    #pragma unroll
    for (int ni=0;ni<4;++ni) bfr[ni] = *(const short8*)(Bld + (wn*64+ni*16+lr)*32 + lg*8);
    #pragma unroll
    for (int mi=0;mi<4;++mi)
      #pragma unroll
      for (int ni=0;ni<4;++ni)
        acc[mi][ni] = mfma16(af[mi], bfr[ni], acc[mi][ni]);
  }
  #pragma unroll
  for (int mi=0;mi<4;++mi){
    int m0 = (int)Mbase + wm*64 + mi*16 + lg*4;
    int t = m0>>6, b = m0&63;
    #pragma unroll
    for (int ni=0;ni<4;++ni){
      int col = Nbase + wn*64 + ni*16 + lr;
      u16x4 u = { f2bf(acc[mi][ni][0]), f2bf(acc[mi][ni][1]),
                  f2bf(acc[mi][ni][2]), f2bf(acc[mi][ni][3]) };
      *(u16x4*)(Xg + ((size_t)t*3072 + col)*64 + b) = u;
    }
  }
}

// ---- phase 2: ONE LSTM STEP per launch (kernel boundary = barrier; no spins,
// nothing can hang). 96 WGs; WG s owns j in [s*8, s*8+8) for all 4 gates.
// Wh read directly from global (L2-resident, 4.7 MB). c state in global fp32.
__global__ __launch_bounds__(256) void k_step(const unsigned short* __restrict__ Xg,
     const unsigned short* __restrict__ Whb, const float* __restrict__ ball,
     const unsigned short* __restrict__ hprev, unsigned short* __restrict__ hnext,
     float* __restrict__ cbuf, float* __restrict__ out, int t){
  __shared__ __align__(16) float comb[2*64*16];     // K-half partial exchange
  int s = blockIdx.x, tid = threadIdx.x, w = tid>>6, l = tid&63;
  int jbase = s*8;
  int mhalf = w&1, khalf = w>>1;
  int lr = l&15, lg = l>>4, jj = l&7;
  bool act = (w<2) && ((l&8)==0);

  // B-operand rows (Wh): staged-row n -> global row (n>>3)*768 + jbase + (n&7)
  size_t grow0 = (size_t)((lr>>3)*768 + jbase + (lr&7)) * 768;   // rows 0..15 (gates f,i)
  size_t grow1 = grow0 + 1536UL*768;                             // rows 16..31 (gates g,o)

  // prefetch epilogue operands (hide latency under MFMA)
  float bias[4]; int colg[4];
  u16x4 xg[2][4];
  float cold[2][4];
  if (w<2){
    #pragma unroll
    for (int g=0; g<4; ++g){ colg[g] = g*768 + jbase + jj; bias[g] = ball[colg[g]]; }
    #pragma unroll
    for (int mi=0;mi<2;++mi){
      int b0r = mhalf*32 + mi*16 + lg*4;
      #pragma unroll
      for (int g=0;g<4;++g)
        xg[mi][g] = *(const u16x4*)(Xg + ((size_t)t*3072 + colg[g])*64 + b0r);
      #pragma unroll
      for (int r=0;r<4;++r)
        cold[mi][r] = cbuf[(size_t)(b0r + r)*768 + jbase + jj];
    }
  }

  f32x4 acc[2][2];
  #pragma unroll
  for(int a=0;a<2;++a){
    #pragma unroll
    for(int b2=0;b2<2;++b2) acc[a][b2]=(f32x4){0.f,0.f,0.f,0.f};
  }
  #pragma unroll
  for (int u=0;u<12;++u){
    int kk = khalf*12+u;
    int ko = kk*32 + lg*8;
    short8 a0 = *(const short8*)(hprev + (mhalf*32 + lr)*768 + ko);
    short8 a1 = *(const short8*)(hprev + (mhalf*32 + 16 + lr)*768 + ko);
    short8 b0 = *(const short8*)(Whb + grow0 + ko);
    short8 b1 = *(const short8*)(Whb + grow1 + ko);
    acc[0][0] = mfma16(a0, b0, acc[0][0]);
    acc[0][1] = mfma16(a0, b1, acc[0][1]);
    acc[1][0] = mfma16(a1, b0, acc[1][0]);
    acc[1][1] = mfma16(a1, b1, acc[1][1]);
  }
  if (w>=2){   // K-half 1: export partials
    #pragma unroll
    for (int mi=0;mi<2;++mi)
      #pragma unroll
      for (int ni=0;ni<2;++ni)
        *(f32x4*)&comb[(((w-2)*64 + l)*16) + (mi*2+ni)*4] = acc[mi][ni];
  }
  __syncthreads();
  if (w>=2) return;
  #pragma unroll
  for (int mi=0;mi<2;++mi)
    #pragma unroll
    for (int ni=0;ni<2;++ni)
      acc[mi][ni] += *(const f32x4*)&comb[((w*64 + l)*16) + (mi*2+ni)*4];
  // epilogue: staged row n = gate*8+jj -> f,g in lanes with l&8==0; i,o in l^8
  #pragma unroll
  for (int mi=0;mi<2;++mi){
    #pragma unroll
    for (int r=0;r<4;++r){
      float a0 = acc[mi][0][r], a1 = acc[mi][1][r];
      float p0 = __shfl_xor(a0, 8);
      float p1 = __shfl_xor(a1, 8);
      float fp = a0 + bf2f(xg[mi][0][r]) + bias[0];
      float ip = p0 + bf2f(xg[mi][1][r]) + bias[1];
      float gp = a1 + bf2f(xg[mi][2][r]) + bias[2];
      float op = p1 + bf2f(xg[mi][3][r]) + bias[3];
      float fv = sigm(fp), iv = sigm(ip), gv = tanh_s(gp), ov = sigm(op);
      float cn = fv*cold[mi][r] + iv*gv;
      float hv = ov * tanh_s(cn);
      if (act){
        int b = mhalf*32 + mi*16 + lg*4 + r;
        int j = jbase + jj;
        cbuf[(size_t)b*768 + j] = cn;
        out[((size_t)t*64 + b)*768 + j] = hv;
        hnext[(size_t)b*768 + j] = f2bf(hv);
        if (t==511){
          out[(512UL*64 + b)*768 + j] = hv;        // hT
          out[(512UL*64 + 64 + b)*768 + j] = cn;   // cT
        }
      }
    }
  }
}

extern "C" void kernel_launch(void* const* d_in, const int* in_sizes, int n_in,
                              void* d_out, int out_size, void* d_ws, size_t ws_size,
                              hipStream_t stream){
  const float* x   = (const float*)d_in[0];
  const float* Wf  = (const float*)d_in[1];
  const float* bf_ = (const float*)d_in[2];
  const float* Wi  = (const float*)d_in[3];
  const float* bi_ = (const float*)d_in[4];
  const float* Wg  = (const float*)d_in[5];
  const float* bg_ = (const float*)d_in[6];
  const float* Wo  = (const float*)d_in[7];
  const float* bo_ = (const float*)d_in[8];
  char* ws = (char*)d_ws;
  if (ws_size < OFF_CST + SZ_CST) return;  // need ~262 MB scratch
  unsigned short* xb   = (unsigned short*)(ws + OFF_XBF);
  unsigned short* Wxb  = (unsigned short*)(ws + OFF_WXB);
  unsigned short* Whb  = (unsigned short*)(ws + OFF_WHB);
  float*          ball = (float*)(ws + OFF_BALL);
  unsigned short* Xg   = (unsigned short*)(ws + OFF_XG);
  unsigned short* hbuf = (unsigned short*)(ws + OFF_HBUF);
  float*          cbuf = (float*)(ws + OFF_CST);
  float* out = (float*)d_out;

  hipMemsetAsync(hbuf, 0, SZ_HBUF + SZ_CST, stream);  // h0=0, c0=0 (contiguous)
  k_conv_x<<<24576, 256, 0, stream>>>(x, xb, 6291456);
  k_conv_w<<<2304, 256, 0, stream>>>(Wf, Wi, Wg, Wo, Wxb, Whb);
  k_conv_b<<<12, 256, 0, stream>>>(bf_, bi_, bg_, bo_, ball);
  k_gemm_x<<<6144, 256, 0, stream>>>(xb, Wxb, Xg);
  for (int t=0; t<512; ++t){
    unsigned short* hprev = hbuf + (size_t)(t&1)*(64*768);
    unsigned short* hnext = hbuf + (size_t)((t+1)&1)*(64*768);
    k_step<<<96, 256, 0, stream>>>(Xg, Whb, ball, hprev, hnext, cbuf, out, t);
  }
}